// Round 13
// baseline (266.969 us; speedup 1.0000x reference)
//
#include <hip/hip_runtime.h>
#include <cmath>

#define BB  1024
#define TT  128
#define HH1 512
#define HH2 256
#define CC  18

// d_ws layout (byte offsets)
#define WS_DIG   0ull             // W2 digits: 8x4x16x2x32x16 i8 = 512 KB
#define WS_W3D   524288ull        // W3 digits LDS image: 32 KB
#define WS_MASK  557056ull        // s1 masks[t][row][8 u64] = 8 MB
#define WS_MASK2 8945664ull       // s2 masks[t][row][8 u32] = 4 MB
#define WS_D3    13139968ull      // D3[t][row][c<18] fp32 = 9.4 MB (end ~22.6 MB)

typedef int   v4i  __attribute__((ext_vector_type(4)));
typedef int   v16i __attribute__((ext_vector_type(16)));
typedef unsigned long long ull;

__device__ __forceinline__ v4i expand_bits(unsigned bits) {
  v4i a;
  a.x = (int)((( bits        & 15u) * 0x204081u) & 0x01010101u);
  a.y = (int)((((bits >>  4) & 15u) * 0x204081u) & 0x01010101u);
  a.z = (int)((((bits >>  8) & 15u) * 0x204081u) & 0x01010101u);
  a.w = (int)((((bits >> 12) & 15u) * 0x204081u) & 0x01010101u);
  return a;
}

// ---- merged front end: W2 digits | W3 digits | bit-exact layer-1 masks.
__global__ __launch_bounds__(256) void phase_front(const float* __restrict__ W2,
    const float* __restrict__ W3, const float* __restrict__ x,
    const float* __restrict__ W1, const float* __restrict__ b1,
    signed char* __restrict__ dig, signed char* __restrict__ w3d,
    ull* __restrict__ masks)
{
  const int blk = blockIdx.x, tid = threadIdx.x;
  if (blk < 2048) {
    // W2 -> 4 signed-i8 digit planes of llrint(w*2^32), layout
    // [stripe(8)][d(4)][s(16)][h(2)][n(32)][j(16)]; h1=s*32+h*16+j, h2=stripe*32+n
    int i = blk * 256 + tid;                       // [0, 524288)
    int j = i & 15, n = (i >> 4) & 31, h = (i >> 9) & 1;
    int s = (i >> 10) & 15, d = (i >> 14) & 3, st = i >> 16;
    int h1 = s * 32 + h * 16 + j;
    int h2 = st * 32 + n;
    float w = W2[h2 * HH1 + h1];
    long long ll = llrint((double)w * 4294967296.0);
    int v = (int)ll;
    signed char d0 = (signed char)(v & 255); v = (v - d0) >> 8;
    signed char d1 = (signed char)(v & 255); v = (v - d1) >> 8;
    signed char d2 = (signed char)(v & 255); v = (v - d2) >> 8;
    signed char d3 = (signed char)v;
    dig[i] = (d == 0) ? d0 : (d == 1) ? d1 : (d == 2) ? d2 : d3;
  } else if (blk < 2176) {
    // W3 digits, LDS image [d(4)][c8(8)][h(2)][col(32)][j(16)], 32 KB
    int i = (blk - 2048) * 256 + tid;              // [0, 32768)
    int j = i & 15, col = (i >> 4) & 31, h = (i >> 9) & 1;
    int c8 = (i >> 10) & 7, d = (i >> 13) & 3;
    int h2 = c8 * 32 + h * 16 + j;
    float w = (col < CC) ? W3[col * HH2 + h2] : 0.0f;
    long long ll = llrint((double)w * 4294967296.0);
    int v = (int)ll;
    signed char d0 = (signed char)(v & 255); v = (v - d0) >> 8;
    signed char d1 = (signed char)(v & 255); v = (v - d1) >> 8;
    signed char d2 = (signed char)(v & 255); v = (v - d2) >> 8;
    signed char d3 = (signed char)v;
    w3d[i] = (d == 0) ? d0 : (d == 1) ? d1 : (d == 2) ? d2 : d3;
  } else {
    // bit-exact layer 1 (mul-rn, add-rn, add-rn), one block per row
    __shared__ float xrow[TT];
    const int row = blk - 2176, wv = tid >> 6, lane = tid & 63;
    for (int i = tid; i < TT; i += 256) xrow[i] = x[row * TT + i];
    const float w1a = W1[tid], w1b = W1[tid + 256];
    const float b1a = b1[tid], b1b = b1[tid + 256];
    float v1a = 0.f, v1b = 0.f;
    __syncthreads();
    for (int t = 0; t < TT; ++t) {
      float xt = xrow[t];
      float iA = __fadd_rn(__fmul_rn(xt, w1a), b1a);
      v1a = __fadd_rn(v1a, iA);
      bool sA = (v1a >= 1.0f);  v1a = sA ? (v1a - 1.0f) : v1a;
      float iB = __fadd_rn(__fmul_rn(xt, w1b), b1b);
      v1b = __fadd_rn(v1b, iB);
      bool sB = (v1b >= 1.0f);  v1b = sB ? (v1b - 1.0f) : v1b;
      ull mA = __ballot(sA);
      ull mB = __ballot(sB);
      if (lane == 0) {
        ull* p = masks + ((size_t)t * BB + row) * 8;
        p[wv] = mA; p[4 + wv] = mB;
      }
    }
  }
}

// ---- fused layer 2: 16 symmetric waves (4/SIMD), phase-alternating.
// GEMM phase: wave (ts=wv&7, pair=wv>>3) computes t=c*8+ts, planes
// {2pair, 2pair+1} (16 expands, 32 MFMA, B from LDS), i32 pair-fold
// (exact: acc0+(acc1<<8)) -> pbuf. Scan phase: each thread owns one
// (row,col) cell, scans 8 t (exact f64 fold -> one f32 rounding,
// bit-identical to R4 chain), ballots s2 masks; next-chunk masks are
// prefetched into the freed wt regs under the scan. 2 barriers/chunk.
__global__ __launch_bounds__(1024, 4) void phase_gemmscan(
    const signed char* __restrict__ Bd, const ull* __restrict__ masks,
    const float* __restrict__ b2, unsigned* __restrict__ masks2)
{
  __shared__ __align__(16) signed char Bl[65536];
  __shared__ int pbuf[8][2][32 * 33];              // [tl][pair][col*33+rowl] 67.6 KB

  const int bid = blockIdx.x;
  const int rowtile = bid & 31, stripe = bid >> 5; // stripe-siblings: same XCD
  const int tid = threadIdx.x, lane = tid & 63, wv = tid >> 6;  // wv 0..15
  const int half = lane >> 5;

  {
    const uint4* src = (const uint4*)(Bd + (size_t)stripe * 65536);
    uint4* dst = (uint4*)Bl;
#pragma unroll
    for (int i = 0; i < 4; ++i) dst[tid + 1024 * i] = src[tid + 1024 * i];
  }

  const int ts   = wv & 7;                         // t-slot 0..7
  const int pair = wv >> 3;                        // 0,1 -> planes 2p,2p+1
  const int arow = rowtile * 32 + (lane & 31);
  const int hsh  = half * 16;
  const signed char* b0 = Bl + (2 * pair    ) * 16384 + half * 512 + (lane & 31) * 16;
  const signed char* b1 = Bl + (2 * pair + 1) * 16384 + half * 512 + (lane & 31) * 16;

  // scan mapping: thread owns cell (row = wv*2+half, col = lane&31)
  const int srow = wv * 2 + half;
  const int scol = lane & 31;
  const float b2r = b2[stripe * 32 + scol];
  float v2 = 0.f;

  // prefetch chunk-0 masks
  ull wt[8];
  {
    const ull* p = masks + ((size_t)ts * BB + arow) * 8;
#pragma unroll
    for (int k = 0; k < 8; ++k) wt[k] = p[k];
  }

  __syncthreads();                                 // Bl ready

  for (int c = 0; c < 16; ++c) {
    // ---- GEMM phase ----
    v16i a0 = (v16i){0,0,0,0,0,0,0,0,0,0,0,0,0,0,0,0};
    v16i a1 = (v16i){0,0,0,0,0,0,0,0,0,0,0,0,0,0,0,0};
#pragma unroll
    for (int s = 0; s < 16; ++s) {
      v4i q0 = *(const v4i*)(b0 + s * 1024);
      v4i q1 = *(const v4i*)(b1 + s * 1024);
      unsigned shift = ((s & 1) << 5) + hsh;
      v4i a = expand_bits((unsigned)(wt[s >> 1] >> shift) & 0xFFFFu);
      a0 = __builtin_amdgcn_mfma_i32_32x32x32_i8(a, q0, a0, 0, 0, 0);
      a1 = __builtin_amdgcn_mfma_i32_32x32x32_i8(a, q1, a1, 0, 0, 0);
    }
    // exact i32 pair-fold -> pbuf (b128 stores, conflict-free stride 33)
    {
      int* dst = &pbuf[ts][pair][(lane & 31) * 33];
#pragma unroll
      for (int g = 0; g < 4; ++g) {
        v4i f;
#pragma unroll
        for (int u = 0; u < 4; ++u) {
          int r = g * 4 + u;
          f[u] = a0[r] + (a1[r] << 8);             // exact i32
        }
        *(v4i*)&dst[8 * g + 4 * half] = f;
      }
    }
    __syncthreads();                               // A: pbuf complete

    // prefetch next-chunk masks into freed wt (hidden under scan)
    {
      const int cn = (c + 1 < 16) ? c + 1 : 15;
      const ull* p = masks + ((size_t)(cn * 8 + ts) * BB + arow) * 8;
#pragma unroll
      for (int k = 0; k < 8; ++k) wt[k] = p[k];
    }

    // ---- scan phase: 8 t, cell (srow, scol) ----
    const int tb = c * 8;
#pragma unroll
    for (int tl = 0; tl < 8; ++tl) {
      int slo = pbuf[tl][0][scol * 33 + srow];     // planes 0+(1<<8), exact
      int shi = pbuf[tl][1][scol * 33 + srow];     // planes 2+(3<<8), exact
      double ss = fma((double)shi, 65536.0, (double)slo);   // exact
      float d2 = (float)(ss * 0x1p-32);                     // one rounding
      float i2 = __fadd_rn(d2, b2r);
      v2 = __fadd_rn(v2, i2);
      bool s2 = (v2 >= 1.0f);
      v2 = s2 ? (v2 - 1.0f) : v2;
      ull m = __ballot(s2);                        // lo32: row wv*2, hi32: wv*2+1
      if (lane == 0)
        masks2[((size_t)(tb + tl) * BB + rowtile * 32 + srow) * 8 + stripe]
            = (unsigned)m;
      else if (lane == 32)
        masks2[((size_t)(tb + tl) * BB + rowtile * 32 + srow) * 8 + stripe]
            = (unsigned)(m >> 32);
    }
    __syncthreads();                               // B: pbuf consumed
  }
}

// ---- layer 3: D3[t] = S2[t] @ W3^T, exact i8 MFMA. Block: 32 rows x 8 t.
__global__ __launch_bounds__(512, 2) void phase_l3(const signed char* __restrict__ W3d,
    const unsigned* __restrict__ masks2, float* __restrict__ D3)
{
  __shared__ __align__(16) signed char Bl[32768];
  const int bid = blockIdx.x;
  const int rowtile = bid & 31, tgrp = bid >> 5;   // tgrp 0..15
  const int tid = threadIdx.x, lane = tid & 63, wv = tid >> 6;  // wv 0..7
  const int half = lane >> 5;
  const int t = tgrp * 8 + wv;
  const int row = rowtile * 32 + (lane & 31);

  {
    const uint4* src = (const uint4*)W3d;
    uint4* dst = (uint4*)Bl;
#pragma unroll
    for (int i = 0; i < 4; ++i) dst[tid + 512 * i] = src[tid + 512 * i];
  }

  unsigned words[8];
  {
    const unsigned* mp = masks2 + ((size_t)t * BB + row) * 8;
#pragma unroll
    for (int k = 0; k < 8; ++k) words[k] = mp[k];
  }
  __syncthreads();

  const signed char* bbase = Bl + half * 512 + (lane & 31) * 16;
  v16i acc[4];
#pragma unroll
  for (int d = 0; d < 4; ++d) acc[d] = (v16i){0,0,0,0,0,0,0,0,0,0,0,0,0,0,0,0};

#pragma unroll
  for (int c8 = 0; c8 < 8; ++c8) {
    v4i a = expand_bits((words[c8] >> (half * 16)) & 0xFFFFu);
#pragma unroll
    for (int d = 0; d < 4; ++d) {
      v4i b = *(const v4i*)(bbase + ((d * 8 + c8) * 2) * 512);
      acc[d] = __builtin_amdgcn_mfma_i32_32x32x32_i8(a, b, acc[d], 0, 0, 0);
    }
  }

  const int col = lane & 31;
#pragma unroll
  for (int r = 0; r < 16; ++r) {
    int slo = acc[0][r] + (acc[1][r] << 8);
    int shi = acc[2][r] + (acc[3][r] << 8);
    double ss = fma((double)shi, 65536.0, (double)slo);
    float d3v = (float)(ss * 0x1p-32);
    int rowl = (r & 3) + 8 * (r >> 2) + 4 * half;
    int grow = rowtile * 32 + rowl;
    if (col < CC) D3[((size_t)t * BB + grow) * CC + col] = d3v;
  }
}

// ---- v3/acc scan + output. thread=(row,c); 4-deep prefetch ring; grid 72.
__global__ __launch_bounds__(256) void phase_v3(const float* __restrict__ D3,
    const float* __restrict__ b3, float* __restrict__ out)
{
  int g = blockIdx.x * 256 + threadIdx.x;         // [0, 18432)
  int row = g / CC, c = g - row * CC;
  const float b3r = b3[c];
  float v3 = 0.f, acc = 0.f;
  float buf[4];
#pragma unroll
  for (int p = 0; p < 4; ++p) buf[p] = D3[(size_t)p * (BB * CC) + g];
  for (int t = 0; t < TT; ++t) {
    float d3 = buf[t & 3];
    if (t + 4 < TT) buf[t & 3] = D3[(size_t)(t + 4) * (BB * CC) + g];
    float i3 = __fadd_rn(d3, b3r);
    v3 = __fadd_rn(v3, i3);
    bool s3 = (v3 >= 1.0f);  v3 = s3 ? (v3 - 1.0f) : v3;
    acc = __fadd_rn(acc, s3 ? 1.0f : 0.0f);
  }
  out[g] = acc * (1.0f / TT);
}

extern "C" void kernel_launch(void* const* d_in, const int* in_sizes, int n_in,
                              void* d_out, int out_size, void* d_ws, size_t ws_size,
                              hipStream_t stream)
{
  (void)in_sizes; (void)n_in; (void)out_size; (void)ws_size;
  const float* x  = (const float*)d_in[0];
  const float* W1 = (const float*)d_in[1];
  const float* b1 = (const float*)d_in[2];
  const float* W2 = (const float*)d_in[3];
  const float* b2 = (const float*)d_in[4];
  const float* W3 = (const float*)d_in[5];
  const float* b3 = (const float*)d_in[6];
  // d_in[7] = repeat (structurally 1 for this problem shape)
  float* out = (float*)d_out;
  char*  ws  = (char*)d_ws;

  signed char* dig    = (signed char*)(ws + WS_DIG);
  signed char* w3dig  = (signed char*)(ws + WS_W3D);
  ull*         masks  = (ull*)(ws + WS_MASK);
  unsigned*    masks2 = (unsigned*)(ws + WS_MASK2);
  float*       D3     = (float*)(ws + WS_D3);

  phase_front<<<3200, 256, 0, stream>>>(W2, W3, x, W1, b1, dig, w3dig, masks);
  phase_gemmscan<<<256, 1024, 0, stream>>>(dig, masks, b2, masks2);
  phase_l3<<<512, 512, 0, stream>>>(w3dig, masks2, D3);
  phase_v3<<<72, 256, 0, stream>>>(D3, b3, out);
}